// Round 8
// baseline (94.903 us; speedup 1.0000x reference)
//
#include <hip/hip_runtime.h>

// GarNet: B=64 V=4096 F=16 A=8 P=16 NF=16. Inputs f32 (R2-confirmed), output f32.
// R7 lesson (cycle model): LDS pipe congestion from broadcast weight/M re-reads
// (32 b128/vertex) dominated both kernels. R8: weights/M via scalar/global path,
// S=4 ownership in k_agg phase 2 (2 b128 -> 16 FMA per vertex), k_out caches its
// M n-quad column in VGPRs (8 b128 once) and streams e->out with zero hot-loop LDS.
//
//   G[b,a,f]=sum_v ew*d, E=sum_v ew ; agg=(Wflr^T G + bflr E)/V ; M=agg*Wout
//   out[v,n]= mask*bout[n] + sum_a ew[v,a]*M[a,n]      (cached ew==0 when masked)

#define B_ 64
#define V_ 4096
#define F_ 16
#define A_ 8
#define P_ 16
#define NF_ 16
#define SPLIT1 8              // k_agg: 8 blocks/batch -> 512 blocks
#define SPLIT2 8              // k_out: 8 blocks/batch -> 512 blocks
#define GE_ (A_*F_ + A_)      // 136 partials per k_agg block
#define ESTR 12               // e_lds row stride (floats)
#define DSTR 20               // d_lds row stride (floats)
#define GSL 132               // gred slice stride (8 groups * 16 + 4 pad)

typedef unsigned int uint32;
typedef unsigned short u16;

__device__ __forceinline__ float bflo(uint32 u){ union{uint32 i;float f;}x; x.i=u<<16; return x.f; }
__device__ __forceinline__ float bfhi(uint32 u){ union{uint32 i;float f;}x; x.i=u&0xffff0000u; return x.f; }

// dtype probe (R2: votes f32 on this harness; kept as cheap insurance)
__device__ __forceinline__ bool detect_bf16(const void* data){
  const uint32* w = (const uint32*)data;
  int c = 0;
  #pragma unroll
  for (int i=0;i<16;++i){
    uint32 e = (w[i]>>7) & 0xffu;
    c += (e>=100u && e<=135u) ? 1 : 0;
  }
  return c >= 11;
}

template<bool BF16>
__device__ __forceinline__ float ldw(const void* p, int i){
  return BF16 ? bflo((uint32)((const u16*)p)[i]) : ((const float*)p)[i];
}

template<bool BF16>
__device__ __forceinline__ void load_vertex(const void* base, size_t v, float* d){
  if (BF16){
    const uint4* p = (const uint4*)((const u16*)base + v*F_);
    uint4 r0=p[0], r1=p[1];
    d[0]=bflo(r0.x); d[1]=bfhi(r0.x); d[2]=bflo(r0.y); d[3]=bfhi(r0.y);
    d[4]=bflo(r0.z); d[5]=bfhi(r0.z); d[6]=bflo(r0.w); d[7]=bfhi(r0.w);
    d[8]=bflo(r1.x); d[9]=bfhi(r1.x); d[10]=bflo(r1.y); d[11]=bfhi(r1.y);
    d[12]=bflo(r1.z); d[13]=bfhi(r1.z); d[14]=bflo(r1.w); d[15]=bfhi(r1.w);
  } else {
    const float4* p = (const float4*)((const float*)base + v*F_);
    float4 a=p[0], b=p[1], c=p[2], e=p[3];
    d[0]=a.x; d[1]=a.y; d[2]=a.z; d[3]=a.w;
    d[4]=b.x; d[5]=b.y; d[6]=b.z; d[7]=b.w;
    d[8]=c.x; d[9]=c.y; d[10]=c.z; d[11]=c.w;
    d[12]=e.x; d[13]=e.y; d[14]=e.z; d[15]=e.w;
  }
}

// ---------------- Kernel A: G[a,f], E[a] per (batch, split); cache e ----------------
template<bool BF16>
__device__ __forceinline__ void agg_body(
    const void* __restrict__ data, const int* __restrict__ nv,
    const void* __restrict__ Ws, const void* __restrict__ bs,
    float* __restrict__ partial, uint4* __restrict__ ecache)
{
  __shared__ __align__(16) float e_lds[256*ESTR];   // 12 KB, e[v][a]
  __shared__ __align__(16) float d_lds[256*DSTR];   // 20 KB, d[v][f]
  __shared__ __align__(16) float gred[32*GSL];      // 16.5 KB, [slice][group][16]
  __shared__ float ered2[16*8];

  const int tid = threadIdx.x;
  const int b = blockIdx.x >> 3;
  const int s = blockIdx.x & 7;
  const int nvb = nv[b];

  const int vbase = s*(V_/SPLIT1);       // 512 vertices per block, 2 tiles of 256
  const size_t voff = (size_t)b*V_ + vbase;

  // phase-2 ownership: group g = (a-quad, f-quad), strided slice c of 8 vertices
  const int g   = tid & 7;
  const int c   = tid >> 3;
  const int ga2 = g >> 2;                // a-quad index (0/1)
  const int gf  = g & 3;                 // f-quad index

  float4 acc0 = make_float4(0,0,0,0);    // acc[j][k]: a=ga2*4+j, f=gf*4+k
  float4 acc1 = make_float4(0,0,0,0);
  float4 acc2 = make_float4(0,0,0,0);
  float4 acc3 = make_float4(0,0,0,0);
  float E[A_];
  #pragma unroll
  for (int a=0;a<A_;++a) E[a]=0.f;

  #pragma unroll
  for (int T=0; T<2; ++T) {
    // ---- phase 1: my vertex -> e[8] (weights via global/scalar path) ----
    const int vl = T*256 + tid;
    float d0[16];
    load_vertex<BF16>(data, voff+vl, d0);
    const float m = (vbase+vl < nvb) ? 1.f : 0.f;

    float t0[A_];
    #pragma unroll
    for (int a=0;a<A_;++a) t0[a] = ldw<BF16>(bs, a);
    #pragma unroll
    for (int f=0; f<F_; ++f){
      const float df = d0[f];
      #pragma unroll
      for (int a=0;a<A_;++a)
        t0[a] = fmaf(df, ldw<BF16>(Ws, f*A_+a), t0[a]);
    }
    float e0[A_];
    #pragma unroll
    for (int a=0;a<A_;++a){
      e0[a] = m*__expf(-t0[a]*t0[a]);
      E[a] += e0[a];
    }
    {   // e-cache: u16 fixed-point, e in [0,1] -> abs err <= 7.6e-6
      const uint32 q0 = __float2uint_rn(e0[0]*65535.f) | (__float2uint_rn(e0[1]*65535.f)<<16);
      const uint32 q1 = __float2uint_rn(e0[2]*65535.f) | (__float2uint_rn(e0[3]*65535.f)<<16);
      const uint32 q2 = __float2uint_rn(e0[4]*65535.f) | (__float2uint_rn(e0[5]*65535.f)<<16);
      const uint32 q3 = __float2uint_rn(e0[6]*65535.f) | (__float2uint_rn(e0[7]*65535.f)<<16);
      ecache[voff+vl] = make_uint4(q0,q1,q2,q3);
    }
    float* er = &e_lds[tid*ESTR];
    *(float4*)(er)   = make_float4(e0[0],e0[1],e0[2],e0[3]);
    *(float4*)(er+4) = make_float4(e0[4],e0[5],e0[6],e0[7]);
    float* dr = &d_lds[tid*DSTR];
    *(float4*)(dr)    = make_float4(d0[0],d0[1],d0[2],d0[3]);
    *(float4*)(dr+4)  = make_float4(d0[4],d0[5],d0[6],d0[7]);
    *(float4*)(dr+8)  = make_float4(d0[8],d0[9],d0[10],d0[11]);
    *(float4*)(dr+12) = make_float4(d0[12],d0[13],d0[14],d0[15]);
    __syncthreads();

    // ---- phase 2: (a-quad, f-quad) over 8 strided vertices: 2 b128 -> 16 FMA ----
    #pragma unroll
    for (int i=0;i<8;++i){
      const int v = c + (i<<5);          // strided: lanes hit distinct banks
      const float4 e4 = *(const float4*)&e_lds[v*ESTR + ga2*4];
      const float4 d4 = *(const float4*)&d_lds[v*DSTR + gf*4];
      acc0.x = fmaf(e4.x, d4.x, acc0.x); acc0.y = fmaf(e4.x, d4.y, acc0.y);
      acc0.z = fmaf(e4.x, d4.z, acc0.z); acc0.w = fmaf(e4.x, d4.w, acc0.w);
      acc1.x = fmaf(e4.y, d4.x, acc1.x); acc1.y = fmaf(e4.y, d4.y, acc1.y);
      acc1.z = fmaf(e4.y, d4.z, acc1.z); acc1.w = fmaf(e4.y, d4.w, acc1.w);
      acc2.x = fmaf(e4.z, d4.x, acc2.x); acc2.y = fmaf(e4.z, d4.y, acc2.y);
      acc2.z = fmaf(e4.z, d4.z, acc2.z); acc2.w = fmaf(e4.z, d4.w, acc2.w);
      acc3.x = fmaf(e4.w, d4.x, acc3.x); acc3.y = fmaf(e4.w, d4.y, acc3.y);
      acc3.z = fmaf(e4.w, d4.z, acc3.z); acc3.w = fmaf(e4.w, d4.w, acc3.w);
    }
    __syncthreads();                     // LDS reused next tile
  }

  // ---- reductions ----
  {
    float* gb = &gred[c*GSL + g*16];
    *(float4*)(gb)    = acc0;
    *(float4*)(gb+4)  = acc1;
    *(float4*)(gb+8)  = acc2;
    *(float4*)(gb+12) = acc3;
  }
  float* er = &e_lds[tid*ESTR];          // E rows (phase 2 done reading e_lds)
  *(float4*)(er)   = make_float4(E[0],E[1],E[2],E[3]);
  *(float4*)(er+4) = make_float4(E[4],E[5],E[6],E[7]);
  __syncthreads();

  if (tid < 128){                        // G[a][f]: sum 32 slices
    const int a = tid >> 4, f = tid & 15;
    const int gg = (a>>2)*4 + (f>>2);
    const int idx = (a&3)*4 + (f&3);
    float sum = 0.f;
    #pragma unroll 8
    for (int cc=0;cc<32;++cc) sum += gred[cc*GSL + gg*16 + idx];
    partial[(size_t)blockIdx.x*GE_ + a*F_ + f] = sum;
  } else {                               // E stage 1
    const int t2 = tid - 128;
    const int q = t2 >> 3, a = t2 & 7;
    float sum = 0.f;
    #pragma unroll
    for (int i=0;i<16;++i) sum += e_lds[(q*16+i)*ESTR + a];
    ered2[q*8 + a] = sum;
  }
  __syncthreads();
  if (tid < A_){                         // E stage 2
    float sum = 0.f;
    #pragma unroll
    for (int q=0;q<16;++q) sum += ered2[q*8 + tid];
    partial[(size_t)blockIdx.x*GE_ + A_*F_ + tid] = sum;
  }
}

__global__ __launch_bounds__(256, 2) void k_agg(
    const void* __restrict__ data, const int* __restrict__ nv,
    const void* __restrict__ Ws, const void* __restrict__ bs,
    float* __restrict__ partial, uint4* __restrict__ ecache)
{
  if (detect_bf16(data)) agg_body<true >(data, nv, Ws, bs, partial, ecache);
  else                   agg_body<false>(data, nv, Ws, bs, partial, ecache);
}

// ------------- Kernel B: agg->M per batch, stream e-cache -> out -------------
template<bool BF16>
__device__ __forceinline__ void out_body(
    const int* __restrict__ nv,
    const void* __restrict__ Wflr, const void* __restrict__ bflr,
    const void* __restrict__ Wout, const void* __restrict__ bout,
    const float* __restrict__ partial, const uint4* __restrict__ ecache,
    float* __restrict__ out)
{
  __shared__ float sGE[GE_];
  __shared__ float sagg[A_*P_];
  __shared__ __align__(16) float sM[A_*NF_];

  const int tid = threadIdx.x;
  const int b = blockIdx.x >> 3;
  const int s = blockIdx.x & 7;

  if (tid < GE_) {
    const float* pp = partial + (size_t)(b*SPLIT1)*GE_ + tid;
    float v = 0.f;
    #pragma unroll
    for (int k=0;k<SPLIT1;++k) v += pp[(size_t)k*GE_];
    sGE[tid] = v;
  }
  const int nvb = nv[b];
  __syncthreads();

  if (tid < A_*P_) {                     // agg[a,p] (Wflr via global, coalesced in p)
    const int a = tid >> 4, p = tid & 15;
    float acc = sGE[A_*F_ + a] * ldw<BF16>(bflr, p);
    #pragma unroll
    for (int f=0;f<F_;++f) acc = fmaf(sGE[a*F_+f], ldw<BF16>(Wflr, f*P_+p), acc);
    sagg[tid] = acc * (1.0f/(float)V_);
  }
  __syncthreads();
  if (tid < A_*NF_) {                    // M[a,n] (Wout via global, L2-hot)
    const int a = tid >> 4, n = tid & 15;
    float m = 0.f;
    #pragma unroll
    for (int p=0;p<P_;++p)
      m = fmaf(sagg[a*P_+p], ldw<BF16>(Wout, (a*P_+p)*NF_+n), m);
    sM[tid] = m;
  }
  __syncthreads();

  // stream: thread = (vertex-group, n-quad); M column cached in VGPRs (8 b128 once)
  const int vg = tid >> 2, nq = tid & 3;
  float4 Mq[A_];
  #pragma unroll
  for (int a=0;a<A_;++a) Mq[a] = *(const float4*)&sM[a*NF_ + nq*4];
  const float4 bo4 = make_float4(ldw<BF16>(bout,nq*4), ldw<BF16>(bout,nq*4+1),
                                 ldw<BF16>(bout,nq*4+2), ldw<BF16>(bout,nq*4+3));

  const int vbase = s*(V_/SPLIT2);       // 512 vertices per block
  const size_t voff = (size_t)b*V_ + vbase;
  const float k16 = 1.0f/65535.f;

  #pragma unroll
  for (int i=0;i<8;++i){
    const int vl = vg + (i<<6);
    const size_t v = voff + vl;
    const float m = (vbase+vl < nvb) ? 1.f : 0.f;
    const uint4 eu = ecache[v];          // 4 nq-threads broadcast same line
    float e0[A_];
    e0[0] = (float)(eu.x & 0xffffu)*k16;  e0[1] = (float)(eu.x >> 16)*k16;
    e0[2] = (float)(eu.y & 0xffffu)*k16;  e0[3] = (float)(eu.y >> 16)*k16;
    e0[4] = (float)(eu.z & 0xffffu)*k16;  e0[5] = (float)(eu.z >> 16)*k16;
    e0[6] = (float)(eu.w & 0xffffu)*k16;  e0[7] = (float)(eu.w >> 16)*k16;

    float4 o = make_float4(m*bo4.x, m*bo4.y, m*bo4.z, m*bo4.w);
    #pragma unroll
    for (int a=0;a<A_;++a){
      o.x = fmaf(e0[a], Mq[a].x, o.x);
      o.y = fmaf(e0[a], Mq[a].y, o.y);
      o.z = fmaf(e0[a], Mq[a].z, o.z);
      o.w = fmaf(e0[a], Mq[a].w, o.w);
    }
    *(float4*)(out + v*NF_ + nq*4) = o;  // lanes: nq fastest -> fully coalesced
  }
}

__global__ __launch_bounds__(256, 2) void k_out(
    const void* __restrict__ data, const int* __restrict__ nv,
    const void* __restrict__ Wflr, const void* __restrict__ bflr,
    const void* __restrict__ Wout, const void* __restrict__ bout,
    const float* __restrict__ partial, const uint4* __restrict__ ecache,
    float* __restrict__ out)
{
  if (detect_bf16(data))
    out_body<true >(nv, Wflr, bflr, Wout, bout, partial, ecache, out);
  else
    out_body<false>(nv, Wflr, bflr, Wout, bout, partial, ecache, out);
}

extern "C" void kernel_launch(void* const* d_in, const int* in_sizes, int n_in,
                              void* d_out, int out_size, void* d_ws, size_t ws_size,
                              hipStream_t stream) {
  const void* data = d_in[0];
  const int*  nv   = (const int*)d_in[1];
  const void* Wflr = d_in[2];
  const void* bflr = d_in[3];
  const void* Ws   = d_in[4];
  const void* bs   = d_in[5];
  const void* Wout = d_in[6];
  const void* bout = d_in[7];
  float* out = (float*)d_out;
  float* partial = (float*)d_ws;                   // 512*136*4 = 278528 B
  uint4* ecache  = (uint4*)((char*)d_ws + 278528); // 4 MiB, 16B-aligned
  // both regions fully overwritten by k_agg each launch

  hipLaunchKernelGGL(k_agg, dim3(B_*SPLIT1), dim3(256), 0, stream,
                     data, nv, Ws, bs, partial, ecache);
  hipLaunchKernelGGL(k_out, dim3(B_*SPLIT2), dim3(256), 0, stream,
                     data, nv, Wflr, bflr, Wout, bout, partial, ecache, out);
}